// Round 8
// baseline (1444.646 us; speedup 1.0000x reference)
//
#include <hip/hip_runtime.h>
#include <cstdint>
#include <cstddef>

typedef unsigned short u16;
typedef __attribute__((ext_vector_type(8))) short bf16x8;
typedef __attribute__((ext_vector_type(4))) float f32x4;

#define N_TOK 16384
#define DIM   1024
#define HID   4096
#define NEXP  8
#define HR    2048
#define TAU   0.02f
#define MAXMT 264   // upper bound on sum_e ceil(cnt[e]/128); sum cnt = 2N = 32768

__device__ __forceinline__ u16 f2bf(float f) {
  union { float f; uint32_t u; } x; x.f = f;
  uint32_t r = x.u + 0x7FFFu + ((x.u >> 16) & 1u);
  return (u16)(r >> 16);
}
__device__ __forceinline__ float bf2f(u16 u) {
  union { uint32_t u; float f; } x; x.u = ((uint32_t)u) << 16; return x.f;
}

__device__ __forceinline__ void async16(const void* g, const void* l) {
  auto gp = reinterpret_cast<const __attribute__((address_space(1))) uint32_t*>(
      reinterpret_cast<uintptr_t>(g));
  auto lp = reinterpret_cast<__attribute__((address_space(3))) uint32_t*>(
      reinterpret_cast<uintptr_t>(l));
  __builtin_amdgcn_global_load_lds(gp, lp, 16, 0, 0);
}

// bijective XCD-chunk remap (m204): block with dispatch id `flat` (XCD = flat%8)
// processes tile `swz`; each XCD gets a contiguous swz range.
__device__ __forceinline__ unsigned xcd_swz(unsigned flat, unsigned nwg) {
  const unsigned xcd = flat & 7u, lid = flat >> 3;
  const unsigned q = nwg >> 3, r = nwg & 7u;
  return (xcd < r ? xcd * (q + 1u) : r * (q + 1u) + (xcd - r) * q) + lid;
}

// ---------------- transpose + fp32->bf16 convert (optionally hi/lo split) ----
template<bool SPLIT>
__global__ __launch_bounds__(256)
void transpose_cvt(const float* __restrict__ src, u16* __restrict__ hi,
                   u16* __restrict__ lo, int R, int C)
{
  __shared__ float tile[32][33];
  const size_t bofs = (size_t)blockIdx.z * R * C;
  src += bofs; hi += bofs; if (SPLIT) lo += bofs;
  const int tx = threadIdx.x, ty = threadIdx.y;  // (32, 8)
  const int c0 = blockIdx.x * 32, r0 = blockIdx.y * 32;
#pragma unroll
  for (int i = 0; i < 4; ++i)
    tile[ty + i * 8][tx] = src[(size_t)(r0 + ty + i * 8) * C + c0 + tx];
  __syncthreads();
#pragma unroll
  for (int i = 0; i < 4; ++i) {
    float v = tile[tx][ty + i * 8];
    size_t o = (size_t)(c0 + ty + i * 8) * R + r0 + tx;
    u16 h = f2bf(v);
    hi[o] = h;
    if (SPLIT) lo[o] = f2bf(v - bf2f(h));
  }
}

// ---------------- LayerNorm -> xn_hi/xn_lo bf16, out = x (residual init) ----
__global__ __launch_bounds__(256)
void ln_kernel(const float* __restrict__ x, const float* __restrict__ g,
               const float* __restrict__ b, u16* __restrict__ xh,
               u16* __restrict__ xl, float* __restrict__ out)
{
  const int row = blockIdx.x;
  const int t = threadIdx.x;
  const float4 xv = ((const float4*)(x + (size_t)row * DIM))[t];
  float s = xv.x + xv.y + xv.z + xv.w;
  float q = xv.x * xv.x + xv.y * xv.y + xv.z * xv.z + xv.w * xv.w;
#pragma unroll
  for (int off = 32; off; off >>= 1) {
    s += __shfl_down(s, off, 64);
    q += __shfl_down(q, off, 64);
  }
  __shared__ float sm[8];
  __shared__ float mu_s, rs_s;
  const int lane = t & 63, wv = t >> 6;
  if (lane == 0) { sm[wv] = s; sm[wv + 4] = q; }
  __syncthreads();
  if (t == 0) {
    float S = sm[0] + sm[1] + sm[2] + sm[3];
    float Q = sm[4] + sm[5] + sm[6] + sm[7];
    float mu = S * (1.f / DIM);
    float var = Q * (1.f / DIM) - mu * mu;
    mu_s = mu; rs_s = rsqrtf(var + 1e-5f);
  }
  __syncthreads();
  const float mu = mu_s, rs = rs_s;
  const float4 gv = ((const float4*)g)[t];
  const float4 bv = ((const float4*)b)[t];
  float n0 = (xv.x - mu) * rs * gv.x + bv.x;
  float n1 = (xv.y - mu) * rs * gv.y + bv.y;
  float n2 = (xv.z - mu) * rs * gv.z + bv.z;
  float n3 = (xv.w - mu) * rs * gv.w + bv.w;
  ushort4 h, l;
  h.x = f2bf(n0); l.x = f2bf(n0 - bf2f(h.x));
  h.y = f2bf(n1); l.y = f2bf(n1 - bf2f(h.y));
  h.z = f2bf(n2); l.z = f2bf(n2 - bf2f(h.z));
  h.w = f2bf(n3); l.w = f2bf(n3 - bf2f(h.w));
  ((ushort4*)(xh + (size_t)row * DIM))[t] = h;
  ((ushort4*)(xl + (size_t)row * DIM))[t] = l;
  ((float4*)(out + (size_t)row * DIM))[t] = xv;
}

// ---------------- logits = Hr(bf16) @ w2 (fp32), one block per row ----------
__global__ __launch_bounds__(256)
void logits_kernel(const u16* __restrict__ HrB, const float* __restrict__ w2,
                   float* __restrict__ logits)
{
  const int row = blockIdx.x, t = threadIdx.x;
  const u16* h = HrB + (size_t)row * HR;
  const ushort4* hv = (const ushort4*)(h + t * 8);
  ushort4 h0 = hv[0], h1 = hv[1];
  u16 hh[8] = {h0.x, h0.y, h0.z, h0.w, h1.x, h1.y, h1.z, h1.w};
  float p[8] = {0, 0, 0, 0, 0, 0, 0, 0};
#pragma unroll
  for (int j = 0; j < 8; ++j) {
    const int col = t * 8 + j;
    const float v = bf2f(hh[j]);
    const float4* wp = (const float4*)(w2 + (size_t)col * 8);
    float4 a = wp[0], b = wp[1];
    p[0] += v * a.x; p[1] += v * a.y; p[2] += v * a.z; p[3] += v * a.w;
    p[4] += v * b.x; p[5] += v * b.y; p[6] += v * b.z; p[7] += v * b.w;
  }
#pragma unroll
  for (int off = 32; off; off >>= 1)
#pragma unroll
    for (int e = 0; e < 8; ++e) p[e] += __shfl_down(p[e], off, 64);
  __shared__ float sm[4][8];
  const int lane = t & 63, wv = t >> 6;
  if (lane == 0) {
#pragma unroll
    for (int e = 0; e < 8; ++e) sm[wv][e] = p[e];
  }
  __syncthreads();
  if (t < 8)
    logits[(size_t)row * 8 + t] = sm[0][t] + sm[1][t] + sm[2][t] + sm[3][t];
}

__device__ __forceinline__ void load_logits(const float* logits, const float* b2,
                                            int row, float l[8]) {
  const float4* lp = (const float4*)(logits + (size_t)row * 8);
  float4 a = lp[0], b = lp[1];
  l[0] = a.x + b2[0]; l[1] = a.y + b2[1]; l[2] = a.z + b2[2]; l[3] = a.w + b2[3];
  l[4] = b.x + b2[4]; l[5] = b.y + b2[5]; l[6] = b.z + b2[6]; l[7] = b.w + b2[7];
}
__device__ __forceinline__ void top2(const float l[8], int& i0, float& l0,
                                     int& i1, float& l1) {
  i0 = 0; l0 = l[0];
#pragma unroll
  for (int e = 1; e < 8; ++e) if (l[e] > l0) { l0 = l[e]; i0 = e; }
  i1 = -1; l1 = -1e30f;
#pragma unroll
  for (int e = 0; e < 8; ++e) if (e != i0 && l[e] > l1) { l1 = l[e]; i1 = e; }
}

// ---------------- pass1: flag ambiguous rows, zero their logits -------------
__global__ __launch_bounds__(256)
void pass_flag(float* __restrict__ logits, const float* __restrict__ b2,
               int* __restrict__ fixL, int* __restrict__ cntFix)
{
  __shared__ int lcnt;
  __shared__ int base;
  const int t = threadIdx.x;
  const int row = blockIdx.x * 256 + t;
  if (t == 0) lcnt = 0;
  float l[8]; load_logits(logits, b2, row, l);
  int i0, i1; float l0, l1;
  top2(l, i0, l0, i1, l1);
  float l2 = -1e30f;
#pragma unroll
  for (int e = 0; e < 8; ++e)
    if (e != i0 && e != i1 && l[e] > l2) l2 = l[e];
  const bool flag = (l1 - l2) < TAU;
  __syncthreads();
  int r = 0;
  if (flag) r = atomicAdd(&lcnt, 1);
  __syncthreads();
  if (t == 0) base = atomicAdd(cntFix, lcnt);
  __syncthreads();
  if (flag) {
    fixL[base + r] = row;
    float4 z = {0.f, 0.f, 0.f, 0.f};
    ((float4*)(logits + (size_t)row * 8))[0] = z;
    ((float4*)(logits + (size_t)row * 8))[1] = z;
  }
}

// ---------------- pass_count / scan / pass_scatter --------------------------
__global__ __launch_bounds__(256)
void pass_count(const float* __restrict__ logits, const float* __restrict__ b2,
                int* __restrict__ cnts)
{
  __shared__ int lcnt[NEXP];
  const int t = threadIdx.x;
  const int row = blockIdx.x * 256 + t;
  if (t < NEXP) lcnt[t] = 0;
  float l[8]; load_logits(logits, b2, row, l);
  int i0, i1; float l0, l1;
  top2(l, i0, l0, i1, l1);
  __syncthreads();
  atomicAdd(&lcnt[i0], 1);
  atomicAdd(&lcnt[i1], 1);
  __syncthreads();
  if (t < NEXP) atomicAdd(&cnts[t], lcnt[t]);
}

__global__ void scan_kernel(const int* __restrict__ cnts, int* __restrict__ offs,
                            int* __restrict__ tileOffs)
{
  if (threadIdx.x == 0) {
    int s = 0, ts = 0;
#pragma unroll
    for (int e = 0; e < NEXP; ++e) {
      offs[e] = s; s += cnts[e];
      tileOffs[e] = ts; ts += (cnts[e] + 127) >> 7;
    }
    offs[NEXP] = s;
    tileOffs[NEXP] = ts;
  }
}

__global__ __launch_bounds__(256)
void pass_scatter(const float* __restrict__ logits, const float* __restrict__ b2,
                  const int* __restrict__ offs, int* __restrict__ cnts2,
                  int* __restrict__ rowsC, float* __restrict__ gateC)
{
  __shared__ int lcnt[NEXP];
  __shared__ int sbase[NEXP];
  const int t = threadIdx.x;
  const int row = blockIdx.x * 256 + t;
  if (t < NEXP) lcnt[t] = 0;
  float l[8]; load_logits(logits, b2, row, l);
  int i0, i1; float l0, l1;
  top2(l, i0, l0, i1, l1);
  float tt = expf(l1 - l0);            // <= 1
  float g0 = 1.f / (1.f + tt);
  float g1 = tt / (1.f + tt);
  __syncthreads();
  int r0 = atomicAdd(&lcnt[i0], 1);
  int r1 = atomicAdd(&lcnt[i1], 1);
  __syncthreads();
  if (t < NEXP) sbase[t] = atomicAdd(&cnts2[t], lcnt[t]);
  __syncthreads();
  int p0 = offs[i0] + sbase[i0] + r0;
  int p1 = offs[i1] + sbase[i1] + r1;
  rowsC[p0] = row; gateC[p0] = g0;
  rowsC[p1] = row; gateC[p1] = g1;
}

// ============================================================================
// Grouped/dense GEMM v8: 3 BLOCKS/CU. BM=128, BN=128, BK=32. 256 thr = 4 waves
// (2M x 2N), 64x64 out/wave. LDS 48 KiB: A-ring 3x8KB + B-ring 3x8KB -> 3
// blocks/CU (12 waves/CU, __launch_bounds__(256,3)).
// R7 post-mortem: LDS-BW cut (64->48KB/Ktile) changed nothing -> the ~1300
// cyc/slot stall is latency-structural (ds_read latency + lgkm + barrier
// lockstep), covered only by more co-resident blocks (R4->R5 +20% was this
// same m114 mechanism; m201 hits 62% MfmaUtil at identical traffic/FLOP).
// Phase T: {stage tile T+2 (B x2, A x2) | ds_read aF x4 + bF x4 (swizzled) |
//           16 MFMA | counted vmcnt | barrier}.
// vmcnt (4 ops/phase, both rings depth 3, staged T+2, proven end of T+1):
//   endWait(T) proves tile T+1; its newest op issued phase T-1 (or prologue);
//   newer = phase T's 4 -> vmcnt(4) uniform. Prologue stages tiles 0,1 (8 ops),
//   proves tile 0 -> vmcnt(4). Tails: rem==2 -> vmcnt(0) (proves last tile,
//   nothing else in flight); rem==1 -> no wait/barrier (epilogue next).
//   A/B slack: staged phase T, proven end T+1 -> >=1 full phase (~3 kcyc)
//   in flight >> HBM 900 / L3 ~600.
// Ring WAR: write slot (T+2)%3 == (T-1)%3, whose ds_reads drained before
//   MFMA(T-1) < barrier(T-1) < phase-T issues.
// LDS swizzle (u16 col ^= ((row>>3)&1)<<4) via inverse-swizzled GLOBAL source
//   (gload_lds dest linear) + swizzled ds_read; conflicts = 0 (verified R2).
// DENSE=true: plain GEMM (router): mt indexes M/128 tiles directly, e=0.
// EPI 1: Cbf[(off+m), n] = bf16(relu(acc + bias))          (GEMM1 / router)
// EPI 2: atomicAdd(Cf32[rows[m], n], gates[m]*(acc+bias))  (expert GEMM2)
// ============================================================================
template<int EPI, bool GATHER, bool DENSE>
__global__ __launch_bounds__(256, 3)
void gemm_moe(const u16* __restrict__ A0, const u16* __restrict__ B0,
              int lda, int ldb, int K, int NT, int Mdense,
              size_t bStrideE, int biasStrideE,
              const int* __restrict__ counts,
              const int* __restrict__ offs, const int* __restrict__ tileOffs,
              const int* __restrict__ rowsC, const float* __restrict__ gatesC,
              const float* __restrict__ bias,
              u16* __restrict__ Cbf, float* __restrict__ Cf32, int ldc)
{
  const unsigned swz = xcd_swz(blockIdx.x, gridDim.x);
  const int mt = (int)(swz / (unsigned)NT);
  int e, m0, Mq, off;
  if constexpr (DENSE) {
    if (mt >= Mdense / 128) return;
    e = 0; m0 = mt * 128; Mq = Mdense; off = 0;
  } else {
    if (mt >= tileOffs[NEXP]) return;
    e = 0;
#pragma unroll
    for (int i = 1; i < NEXP; ++i) if (tileOffs[i] <= mt) e = i;
    m0 = (mt - tileOffs[e]) * 128;
    Mq = counts[e];
    if (m0 >= Mq) return;
    off = offs[e];
  }
  const int n0 = (int)(swz % (unsigned)NT) * 128;
  const int* rows = DENSE ? nullptr : (rowsC + off);
  const u16* B = B0 + (size_t)e * bStrideE;
  const float* bi = bias + (size_t)e * biasStrideE;

  __shared__ alignas(16) u16 As[3][128 * 32];   // 24 KiB
  __shared__ alignas(16) u16 Bs[3][128 * 32];   // 24 KiB

  const int t = threadIdx.x;          // 0..255
  const int numK = K >> 5;            // 32 or 128 (>= 4)

  // ---- staging: A and B each 2 rounds x 256 thr x 16 B (inv-swz source) ----
  const u16* aptr[2]; const u16* bptr[2]; int sdst[2];
#pragma unroll
  for (int i = 0; i < 2; ++i) {
    const int gdx = i * 256 + t;
    const int r = gdx >> 2;                                    // row 0..127
    const int cb = ((gdx & 3) << 4) ^ (((gdx >> 5) & 1) << 5); // byte-in-row
    const int cs = cb >> 1;                                    // u16 col
    int amc = (m0 + r) < Mq ? (m0 + r) : (Mq - 1);
    const size_t agr = DENSE ? (size_t)(m0 + r)
                             : (GATHER ? (size_t)rows[amc] : (size_t)(off + amc));
    aptr[i] = A0 + agr * lda + cs;
    bptr[i] = B + (size_t)(n0 + r) * ldb + cs;
    sdst[i] = gdx * 8;
  }

  // ---- per-wave fragment geometry: 2M x 2N, 64x64 per wave ----
  const int lane = t & 63, wv = t >> 6;
  const int wm = wv >> 1;            // 0..1
  const int wn = wv & 1;             // 0..1
  const int fr = lane & 15, fq = lane >> 4;

  int aIdx[4], bIdx[4];
#pragma unroll
  for (int mf = 0; mf < 4; ++mf) {
    const int r = wm * 64 + mf * 16 + fr;
    aIdx[mf] = r * 32 + ((fq * 8) ^ (((r >> 3) & 1) << 4));
  }
#pragma unroll
  for (int nf = 0; nf < 4; ++nf) {
    const int rb = wn * 64 + nf * 16 + fr;
    bIdx[nf] = rb * 32 + ((fq * 8) ^ (((rb >> 3) & 1) << 4));
  }

  f32x4 acc[4][4];
#pragma unroll
  for (int i = 0; i < 4; ++i)
#pragma unroll
    for (int j = 0; j < 4; ++j) acc[i][j] = (f32x4){0.f, 0.f, 0.f, 0.f};

  // ---- prologue: tiles 0 and 1 (B x2, A x2 each); prove tile 0 ----
#pragma unroll
  for (int h = 0; h < 2; ++h) {
    async16(bptr[0] + h * 32, &Bs[h][sdst[0]]);
    async16(bptr[1] + h * 32, &Bs[h][sdst[1]]);
    async16(aptr[0] + h * 32, &As[h][sdst[0]]);
    async16(aptr[1] + h * 32, &As[h][sdst[1]]);
  }
  asm volatile("s_waitcnt vmcnt(4)" ::: "memory");
  __builtin_amdgcn_s_barrier();
  __builtin_amdgcn_sched_barrier(0);

  // ---- main K loop: one phase per K-tile, vmcnt(4) uniform ----
  int sR = 0;        // read slot  = T % 3
  int sW = 2;        // write slot = (T+2) % 3
  for (int T = 0; T < numK; ++T) {
    if (T + 2 < numK) {
      async16(bptr[0] + (size_t)(T + 2) * 32, &Bs[sW][sdst[0]]);
      async16(bptr[1] + (size_t)(T + 2) * 32, &Bs[sW][sdst[1]]);
      async16(aptr[0] + (size_t)(T + 2) * 32, &As[sW][sdst[0]]);
      async16(aptr[1] + (size_t)(T + 2) * 32, &As[sW][sdst[1]]);
    }

    const u16* aL = As[sR];
    const u16* bL = Bs[sR];
    bf16x8 aF[4], bF[4];
#pragma unroll
    for (int i = 0; i < 4; ++i) {
      aF[i] = *(const bf16x8*)&aL[aIdx[i]];
      bF[i] = *(const bf16x8*)&bL[bIdx[i]];
    }
    __builtin_amdgcn_s_setprio(1);
#pragma unroll
    for (int mf = 0; mf < 4; ++mf)
#pragma unroll
      for (int nf = 0; nf < 4; ++nf)
        acc[mf][nf] = __builtin_amdgcn_mfma_f32_16x16x32_bf16(
            aF[mf], bF[nf], acc[mf][nf], 0, 0, 0);
    __builtin_amdgcn_s_setprio(0);
    __builtin_amdgcn_sched_barrier(0);

    const int rem = numK - T;
    if (rem >= 3) {
      asm volatile("s_waitcnt vmcnt(4)" ::: "memory");
      __builtin_amdgcn_s_barrier();
      __builtin_amdgcn_sched_barrier(0);
    } else if (rem == 2) {
      asm volatile("s_waitcnt vmcnt(0)" ::: "memory");
      __builtin_amdgcn_s_barrier();
      __builtin_amdgcn_sched_barrier(0);
    }
    // rem == 1: last phase, fall through to epilogue

    sR = (sR == 2) ? 0 : sR + 1;
    sW = (sW == 2) ? 0 : sW + 1;
  }

  // ---- epilogue: C/D layout col = fr, row = fq*4 + reg ----
  float bv[4];
#pragma unroll
  for (int nf = 0; nf < 4; ++nf) bv[nf] = bi[n0 + wn * 64 + nf * 16 + fr];

#pragma unroll
  for (int mf = 0; mf < 4; ++mf)
#pragma unroll
    for (int r = 0; r < 4; ++r) {
      const int m = m0 + wm * 64 + mf * 16 + fq * 4 + r;
      if (m < Mq) {
        if constexpr (EPI == 2) {
          const size_t orow = (size_t)rows[m];
          const float g = gatesC[off + m];
#pragma unroll
          for (int nf = 0; nf < 4; ++nf) {
            const int n = n0 + wn * 64 + nf * 16 + fr;
            atomicAdd(&Cf32[orow * ldc + n], g * (acc[mf][nf][r] + bv[nf]));
          }
        } else {
#pragma unroll
          for (int nf = 0; nf < 4; ++nf) {
            const int n = n0 + wn * 64 + nf * 16 + fr;
            Cbf[(size_t)(off + m) * ldc + n] =
                f2bf(fmaxf(acc[mf][nf][r] + bv[nf], 0.f));
          }
        }
      }
    }
}

// ---------------- GEMM: C[M,N] = A[M,K] * Bt[N,K]^T (bf16 MFMA) -------------
// (legacy 128x128 kernel: fix-GEMM, non-fused fallback)
template<bool SPLIT, int EPI, bool GATHER>
__global__ __launch_bounds__(256, 2)
void gemm_bt(const u16* __restrict__ A0, const u16* __restrict__ A1,
             const u16* __restrict__ B0, const u16* __restrict__ B1,
             int lda, int ldb, int K, int M,
             const int* __restrict__ counts, int expertArg,
             const int* __restrict__ offs,
             const int* __restrict__ rowsC, const float* __restrict__ gatesC,
             const float* __restrict__ bias,
             const float* __restrict__ w2, float* __restrict__ logits,
             u16* __restrict__ Cbf, float* __restrict__ Cf32, int ldc)
{
  int expert, m0, n0;
  if (counts == nullptr) {
    const unsigned nwg = gridDim.x * gridDim.y;
    const unsigned flat = blockIdx.y * gridDim.x + blockIdx.x;
    const unsigned swz = xcd_swz(flat, nwg);
    expert = expertArg;
    m0 = (int)(swz / gridDim.x) * 128;
    n0 = (int)(swz % gridDim.x) * 128;
  } else {
    expert = expertArg;
    m0 = blockIdx.y * 128;
    n0 = blockIdx.x * 128;
  }

  const int Mq = counts ? counts[expert] : M;
  if (m0 >= Mq) return;
  const int off = offs ? offs[expert] : 0;
  const int* rows = rowsC ? rowsC + off : nullptr;
  const float* gates = gatesC ? gatesC + off : nullptr;
  const u16* B = B0;
  const u16* Bl = SPLIT ? B1 : nullptr;
  const float* bi = bias;
  const int z = (int)blockIdx.z;
  const int zOff = z * K;

  __shared__ u16 As0[128 * 32], Bs0[128 * 32];
  __shared__ u16 As1[SPLIT ? 128 * 32 : 8], Bs1[SPLIT ? 128 * 32 : 8];

  const int t = threadIdx.x;
  size_t aoff[2]; int acodd[2]; size_t boff[2];
#pragma unroll
  for (int i = 0; i < 2; ++i) {
    int gdx = i * 256 + t;
    int ar = gdx >> 2, ac = (gdx & 3) * 8;
    int am = m0 + ar;
    int amc = am < Mq ? am : (Mq - 1);
    int agr = GATHER ? rows[amc] : amc;
    aoff[i] = (size_t)agr * lda + ac + zOff;
    boff[i] = (size_t)(n0 + ar) * ldb + ac + zOff;
    acodd[i] = gdx * 8;
  }

  f32x4 acc[4][4];
#pragma unroll
  for (int i = 0; i < 4; ++i)
#pragma unroll
    for (int j = 0; j < 4; ++j) acc[i][j] = (f32x4){0.f, 0.f, 0.f, 0.f};

  const int lane = t & 63, wv = t >> 6;
  const int wm = (wv >> 1) * 64, wn = (wv & 1) * 64;
  const int fr = lane & 15, fq = lane >> 4;

  for (int k0 = 0; k0 < K; k0 += 32) {
    __syncthreads();
#pragma unroll
    for (int i = 0; i < 2; ++i) {
      async16(A0 + aoff[i] + k0, &As0[acodd[i]]);
      async16(B + boff[i] + k0, &Bs0[acodd[i]]);
      if (SPLIT) {
        async16(A1 + aoff[i] + k0, &As1[acodd[i]]);
        async16(Bl + boff[i] + k0, &Bs1[acodd[i]]);
      }
    }
    __syncthreads();
    bf16x8 af[4], bfr[4], af1[4], bf1[4];
#pragma unroll
    for (int xi = 0; xi < 4; ++xi) {
      af[xi]  = *(const bf16x8*)&As0[(wm + xi * 16 + fr) * 32 + fq * 8];
      bfr[xi] = *(const bf16x8*)&Bs0[(wn + xi * 16 + fr) * 32 + fq * 8];
      if (SPLIT) {
        af1[xi] = *(const bf16x8*)&As1[(wm + xi * 16 + fr) * 32 + fq * 8];
        bf1[xi] = *(const bf16x8*)&Bs1[(wn + xi * 16 + fr) * 32 + fq * 8];
      }
    }
#pragma unroll
    for (int mt = 0; mt < 4; ++mt)
#pragma unroll
      for (int nt = 0; nt < 4; ++nt) {
        acc[mt][nt] = __builtin_amdgcn_mfma_f32_16x16x32_bf16(af[mt], bfr[nt], acc[mt][nt], 0, 0, 0);
        if (SPLIT) {
          acc[mt][nt] = __builtin_amdgcn_mfma_f32_16x16x32_bf16(af[mt], bf1[nt], acc[mt][nt], 0, 0, 0);
          acc[mt][nt] = __builtin_amdgcn_mfma_f32_16x16x32_bf16(af1[mt], bfr[nt], acc[mt][nt], 0, 0, 0);
        }
      }
  }

  // C/D layout: col = lane&15 (fr), row = fq*4 + reg
  if constexpr (EPI == 3) {
    float w2v[4][8]; float b1v[4];
#pragma unroll
    for (int nt = 0; nt < 4; ++nt) {
      const int n = n0 + wn + nt * 16 + fr;
      b1v[nt] = bi[n];
      const float4* wp = (const float4*)(w2 + (size_t)n * 8);
      float4 wa = wp[0], wb = wp[1];
      w2v[nt][0] = wa.x; w2v[nt][1] = wa.y; w2v[nt][2] = wa.z; w2v[nt][3] = wa.w;
      w2v[nt][4] = wb.x; w2v[nt][5] = wb.y; w2v[nt][6] = wb.z; w2v[nt][7] = wb.w;
    }
#pragma unroll
    for (int mt = 0; mt < 4; ++mt) {
      float pe[4][8];
#pragma unroll
      for (int r = 0; r < 4; ++r)
#pragma unroll
        for (int ee = 0; ee < 8; ++ee) pe[r][ee] = 0.f;
#pragma unroll
      for (int nt = 0; nt < 4; ++nt)
#pragma unroll
        for (int r = 0; r < 4; ++r) {
          float v = fmaxf(acc[mt][nt][r] + b1v[nt], 0.f);
#pragma unroll
          for (int ee = 0; ee < 8; ++ee) pe[r][ee] += v * w2v[nt][ee];
        }
#pragma unroll
      for (int offx = 1; offx < 16; offx <<= 1)
#pragma unroll
        for (int r = 0; r < 4; ++r)
#pragma unroll
          for (int ee = 0; ee < 8; ++ee)
            pe[r][ee] += __shfl_xor(pe[r][ee], offx, 64);
      if (fr == 0) {
#pragma unroll
        for (int r = 0; r < 4; ++r) {
          const int m = m0 + wm + mt * 16 + fq * 4 + r;
          if (m < Mq) {
            const int lrow = GATHER ? rows[m] : m;
#pragma unroll
            for (int ee = 0; ee < 8; ++ee)
              atomicAdd(&logits[(size_t)lrow * 8 + ee], pe[r][ee]);
          }
        }
      }
    }
    return;
  }

#pragma unroll
  for (int mt = 0; mt < 4; ++mt) {
#pragma unroll
    for (int nt = 0; nt < 4; ++nt) {
      const int n = n0 + wn + nt * 16 + fr;
      const float bvv = (z == 0) ? bi[n] : 0.f;
#pragma unroll
      for (int r = 0; r < 4; ++r) {
        const int m = m0 + wm + mt * 16 + fq * 4 + r;
        if (m < Mq) {
          float v = acc[mt][nt][r] + bvv;
          if constexpr (EPI == 1) {
            Cbf[(size_t)m * ldc + n] = f2bf(fmaxf(v, 0.f));
          } else {
            atomicAdd(&Cf32[(size_t)rows[m] * ldc + n], gates[m] * v);
          }
        }
      }
    }
  }
}

extern "C" void kernel_launch(void* const* d_in, const int* in_sizes, int n_in,
                              void* d_out, int out_size, void* d_ws, size_t ws_size,
                              hipStream_t stream)
{
  const float* x    = (const float*)d_in[0];
  const float* ln_g = (const float*)d_in[1];
  const float* ln_b = (const float*)d_in[2];
  const float* r_w1 = (const float*)d_in[3];
  const float* r_b1 = (const float*)d_in[4];
  const float* r_w2 = (const float*)d_in[5];
  const float* r_b2 = (const float*)d_in[6];
  const float* e_w1 = (const float*)d_in[7];
  const float* e_b1 = (const float*)d_in[8];
  const float* e_w2 = (const float*)d_in[9];
  const float* e_b2 = (const float*)d_in[10];
  float* out = (float*)d_out;

  char* ws = (char*)d_ws;
  const size_t MB = 1024ull * 1024ull;
  u16*   xnhi = (u16*)(ws);                 // 32 MB  [N, D] bf16
  u16*   xnlo = (u16*)(ws + 32 * MB);       // 32 MB
  u16*   rw1h = (u16*)(ws + 64 * MB);       // 4 MB   [HR, D] bf16
  u16*   rw1l = (u16*)(ws + 68 * MB);       // 4 MB
  u16*   ew1t = (u16*)(ws + 72 * MB);       // 64 MB  [E][H, D] bf16
  u16*   ew2t = (u16*)(ws + 136 * MB);      // 64 MB  [E][D, H] bf16
  float* logits = (float*)(ws + 200 * MB);                    // 512 KB [N, 8]
  int*   rowsC  = (int*)(ws + 200 * MB + 512 * 1024);         // 128 KB [2N]
  float* gateC  = (float*)(ws + 200 * MB + 640 * 1024);       // 128 KB [2N]
  int*   fixL   = (int*)(ws + 200 * MB + 768 * 1024);         // 64 KB  [N]
  int*   cntb   = (int*)(ws + 200 * MB + 832 * 1024);         // 256 B
  int*   cnts   = cntb;          // [8]
  int*   cnts2  = cntb + 8;      // [8]
  int*   offs   = cntb + 16;     // [9]
  int*   cntFix = cntb + 25;     // [1]
  int*   tileOffs = cntb + 32;   // [9] per-expert 128-row tile prefix sums
  u16*   Hbuf = (u16*)(ws + 201 * MB);      // fused: 256 MB [2N, H]; HrB aliases
  u16*   HrB  = Hbuf;                       // 64 MB [N, HR] bf16 (router hidden)
  (void)in_sizes; (void)n_in; (void)out_size;

  const bool fused = ws_size >= 458ull * MB;

  hipMemsetAsync(cntb, 0, 256, stream);

  dim3 tb(32, 8);
  transpose_cvt<true ><<<dim3(HR / 32, DIM / 32, 1), tb, 0, stream>>>(r_w1, rw1h, rw1l, DIM, HR);
  transpose_cvt<false><<<dim3(HID / 32, DIM / 32, NEXP), tb, 0, stream>>>(e_w1, ew1t, nullptr, DIM, HID);
  transpose_cvt<false><<<dim3(DIM / 32, HID / 32, NEXP), tb, 0, stream>>>(e_w2, ew2t, nullptr, HID, DIM);

  ln_kernel<<<N_TOK, 256, 0, stream>>>(x, ln_g, ln_b, xnhi, xnlo, out);

  // router: HrB = bf16(relu(xn @ r_w1 + b1)) — v8 DENSE path, 2048 blocks
  gemm_moe<1, false, true><<<dim3((HR / 128) * (N_TOK / 128)), 256, 0, stream>>>(
      xnhi, rw1h, DIM, DIM, DIM, HR / 128, N_TOK, 0, 0,
      nullptr, nullptr, nullptr, nullptr, nullptr, r_b1,
      HrB, nullptr, HR);

  logits_kernel<<<N_TOK, 256, 0, stream>>>(HrB, r_w2, logits);

  pass_flag<<<N_TOK / 256, 256, 0, stream>>>(logits, r_b2, fixL, cntFix);

  // exact recompute (split 3-term) of flagged rows' logits
  gemm_bt<true, 3, true><<<dim3(HR / 128, N_TOK / 128), 256, 0, stream>>>(
      xnhi, xnlo, rw1h, rw1l, DIM, DIM, DIM, N_TOK,
      cntFix, 0, nullptr, fixL, nullptr, r_b1, r_w2, logits,
      nullptr, nullptr, 0);

  pass_count<<<N_TOK / 256, 256, 0, stream>>>(logits, r_b2, cnts);
  scan_kernel<<<1, 64, 0, stream>>>(cnts, offs, tileOffs);
  pass_scatter<<<N_TOK / 256, 256, 0, stream>>>(logits, r_b2, offs, cnts2, rowsC, gateC);

  if (fused) {
    // v8 grouped GEMMs: 128x128 tiles, 3 blocks/CU, flat grid + XCD swizzle
    gemm_moe<1, true, false><<<dim3((HID / 128) * MAXMT), 256, 0, stream>>>(
        xnhi, ew1t, DIM, DIM, DIM, HID / 128, 0,
        (size_t)HID * DIM, HID,
        cnts, offs, tileOffs, rowsC, nullptr, e_b1,
        Hbuf, nullptr, HID);
    gemm_moe<2, false, false><<<dim3((DIM / 128) * MAXMT), 256, 0, stream>>>(
        Hbuf, ew2t, HID, HID, HID, DIM / 128, 0,
        (size_t)DIM * HID, DIM,
        cnts, offs, tileOffs, rowsC, gateC, e_b2,
        nullptr, out, DIM);
  } else {
    for (int e = 0; e < NEXP; ++e) {
      gemm_bt<false, 1, true><<<dim3(HID / 128, N_TOK / 128), 256, 0, stream>>>(
          xnhi, nullptr, ew1t + (size_t)e * HID * DIM, nullptr,
          DIM, DIM, DIM, N_TOK,
          cnts, e, offs, rowsC, nullptr, e_b1 + (size_t)e * HID, nullptr, nullptr,
          Hbuf, nullptr, HID);
      gemm_bt<false, 2, false><<<dim3(DIM / 128, N_TOK / 128, 2), 256, 0, stream>>>(
          Hbuf, nullptr, ew2t + (size_t)e * DIM * HID, nullptr,
          HID, HID, HID / 2, N_TOK,
          cnts, e, offs, rowsC, gateC, e_b2 + (size_t)e * DIM, nullptr, nullptr,
          nullptr, out, DIM);
    }
  }
}

// Round 9
// 1363.162 us; speedup vs baseline: 1.0598x; 1.0598x over previous
//
#include <hip/hip_runtime.h>
#include <cstdint>
#include <cstddef>

typedef unsigned short u16;
typedef __attribute__((ext_vector_type(8))) short bf16x8;
typedef __attribute__((ext_vector_type(4))) float f32x4;

#define N_TOK 16384
#define DIM   1024
#define HID   4096
#define NEXP  8
#define HR    2048
#define TAU   0.02f
#define MAXMT 264   // sum_e ceil(cnt[e]/128) bound (fix/fallback paths)
#define MAXMT2 136  // sum_e ceil(cnt[e]/256) bound: 32768/256 + 7 = 135 -> 136

__device__ __forceinline__ u16 f2bf(float f) {
  union { float f; uint32_t u; } x; x.f = f;
  uint32_t r = x.u + 0x7FFFu + ((x.u >> 16) & 1u);
  return (u16)(r >> 16);
}
__device__ __forceinline__ float bf2f(u16 u) {
  union { uint32_t u; float f; } x; x.u = ((uint32_t)u) << 16; return x.f;
}

__device__ __forceinline__ void async16(const void* g, const void* l) {
  auto gp = reinterpret_cast<const __attribute__((address_space(1))) uint32_t*>(
      reinterpret_cast<uintptr_t>(g));
  auto lp = reinterpret_cast<__attribute__((address_space(3))) uint32_t*>(
      reinterpret_cast<uintptr_t>(l));
  __builtin_amdgcn_global_load_lds(gp, lp, 16, 0, 0);
}

// bijective XCD-chunk remap (m204)
__device__ __forceinline__ unsigned xcd_swz(unsigned flat, unsigned nwg) {
  const unsigned xcd = flat & 7u, lid = flat >> 3;
  const unsigned q = nwg >> 3, r = nwg & 7u;
  return (xcd < r ? xcd * (q + 1u) : r * (q + 1u) + (xcd - r) * q) + lid;
}

// ---------------- transpose + fp32->bf16 convert (optionally hi/lo split) ----
template<bool SPLIT>
__global__ __launch_bounds__(256)
void transpose_cvt(const float* __restrict__ src, u16* __restrict__ hi,
                   u16* __restrict__ lo, int R, int C)
{
  __shared__ float tile[32][33];
  const size_t bofs = (size_t)blockIdx.z * R * C;
  src += bofs; hi += bofs; if (SPLIT) lo += bofs;
  const int tx = threadIdx.x, ty = threadIdx.y;  // (32, 8)
  const int c0 = blockIdx.x * 32, r0 = blockIdx.y * 32;
#pragma unroll
  for (int i = 0; i < 4; ++i)
    tile[ty + i * 8][tx] = src[(size_t)(r0 + ty + i * 8) * C + c0 + tx];
  __syncthreads();
#pragma unroll
  for (int i = 0; i < 4; ++i) {
    float v = tile[tx][ty + i * 8];
    size_t o = (size_t)(c0 + ty + i * 8) * R + r0 + tx;
    u16 h = f2bf(v);
    hi[o] = h;
    if (SPLIT) lo[o] = f2bf(v - bf2f(h));
  }
}

// ---------------- LayerNorm -> xn_hi/xn_lo bf16, out = x (residual init) ----
__global__ __launch_bounds__(256)
void ln_kernel(const float* __restrict__ x, const float* __restrict__ g,
               const float* __restrict__ b, u16* __restrict__ xh,
               u16* __restrict__ xl, float* __restrict__ out)
{
  const int row = blockIdx.x;
  const int t = threadIdx.x;
  const float4 xv = ((const float4*)(x + (size_t)row * DIM))[t];
  float s = xv.x + xv.y + xv.z + xv.w;
  float q = xv.x * xv.x + xv.y * xv.y + xv.z * xv.z + xv.w * xv.w;
#pragma unroll
  for (int off = 32; off; off >>= 1) {
    s += __shfl_down(s, off, 64);
    q += __shfl_down(q, off, 64);
  }
  __shared__ float sm[8];
  __shared__ float mu_s, rs_s;
  const int lane = t & 63, wv = t >> 6;
  if (lane == 0) { sm[wv] = s; sm[wv + 4] = q; }
  __syncthreads();
  if (t == 0) {
    float S = sm[0] + sm[1] + sm[2] + sm[3];
    float Q = sm[4] + sm[5] + sm[6] + sm[7];
    float mu = S * (1.f / DIM);
    float var = Q * (1.f / DIM) - mu * mu;
    mu_s = mu; rs_s = rsqrtf(var + 1e-5f);
  }
  __syncthreads();
  const float mu = mu_s, rs = rs_s;
  const float4 gv = ((const float4*)g)[t];
  const float4 bv = ((const float4*)b)[t];
  float n0 = (xv.x - mu) * rs * gv.x + bv.x;
  float n1 = (xv.y - mu) * rs * gv.y + bv.y;
  float n2 = (xv.z - mu) * rs * gv.z + bv.z;
  float n3 = (xv.w - mu) * rs * gv.w + bv.w;
  ushort4 h, l;
  h.x = f2bf(n0); l.x = f2bf(n0 - bf2f(h.x));
  h.y = f2bf(n1); l.y = f2bf(n1 - bf2f(h.y));
  h.z = f2bf(n2); l.z = f2bf(n2 - bf2f(h.z));
  h.w = f2bf(n3); l.w = f2bf(n3 - bf2f(h.w));
  ((ushort4*)(xh + (size_t)row * DIM))[t] = h;
  ((ushort4*)(xl + (size_t)row * DIM))[t] = l;
  ((float4*)(out + (size_t)row * DIM))[t] = xv;
}

// ---------------- logits = Hr(bf16) @ w2 (fp32), one block per row ----------
__global__ __launch_bounds__(256)
void logits_kernel(const u16* __restrict__ HrB, const float* __restrict__ w2,
                   float* __restrict__ logits)
{
  const int row = blockIdx.x, t = threadIdx.x;
  const u16* h = HrB + (size_t)row * HR;
  const ushort4* hv = (const ushort4*)(h + t * 8);
  ushort4 h0 = hv[0], h1 = hv[1];
  u16 hh[8] = {h0.x, h0.y, h0.z, h0.w, h1.x, h1.y, h1.z, h1.w};
  float p[8] = {0, 0, 0, 0, 0, 0, 0, 0};
#pragma unroll
  for (int j = 0; j < 8; ++j) {
    const int col = t * 8 + j;
    const float v = bf2f(hh[j]);
    const float4* wp = (const float4*)(w2 + (size_t)col * 8);
    float4 a = wp[0], b = wp[1];
    p[0] += v * a.x; p[1] += v * a.y; p[2] += v * a.z; p[3] += v * a.w;
    p[4] += v * b.x; p[5] += v * b.y; p[6] += v * b.z; p[7] += v * b.w;
  }
#pragma unroll
  for (int off = 32; off; off >>= 1)
#pragma unroll
    for (int e = 0; e < 8; ++e) p[e] += __shfl_down(p[e], off, 64);
  __shared__ float sm[4][8];
  const int lane = t & 63, wv = t >> 6;
  if (lane == 0) {
#pragma unroll
    for (int e = 0; e < 8; ++e) sm[wv][e] = p[e];
  }
  __syncthreads();
  if (t < 8)
    logits[(size_t)row * 8 + t] = sm[0][t] + sm[1][t] + sm[2][t] + sm[3][t];
}

__device__ __forceinline__ void load_logits(const float* logits, const float* b2,
                                            int row, float l[8]) {
  const float4* lp = (const float4*)(logits + (size_t)row * 8);
  float4 a = lp[0], b = lp[1];
  l[0] = a.x + b2[0]; l[1] = a.y + b2[1]; l[2] = a.z + b2[2]; l[3] = a.w + b2[3];
  l[4] = b.x + b2[4]; l[5] = b.y + b2[5]; l[6] = b.z + b2[6]; l[7] = b.w + b2[7];
}
__device__ __forceinline__ void top2(const float l[8], int& i0, float& l0,
                                     int& i1, float& l1) {
  i0 = 0; l0 = l[0];
#pragma unroll
  for (int e = 1; e < 8; ++e) if (l[e] > l0) { l0 = l[e]; i0 = e; }
  i1 = -1; l1 = -1e30f;
#pragma unroll
  for (int e = 0; e < 8; ++e) if (e != i0 && l[e] > l1) { l1 = l[e]; i1 = e; }
}

// ---------------- pass1: flag ambiguous rows, zero their logits -------------
__global__ __launch_bounds__(256)
void pass_flag(float* __restrict__ logits, const float* __restrict__ b2,
               int* __restrict__ fixL, int* __restrict__ cntFix)
{
  __shared__ int lcnt;
  __shared__ int base;
  const int t = threadIdx.x;
  const int row = blockIdx.x * 256 + t;
  if (t == 0) lcnt = 0;
  float l[8]; load_logits(logits, b2, row, l);
  int i0, i1; float l0, l1;
  top2(l, i0, l0, i1, l1);
  float l2 = -1e30f;
#pragma unroll
  for (int e = 0; e < 8; ++e)
    if (e != i0 && e != i1 && l[e] > l2) l2 = l[e];
  const bool flag = (l1 - l2) < TAU;
  __syncthreads();
  int r = 0;
  if (flag) r = atomicAdd(&lcnt, 1);
  __syncthreads();
  if (t == 0) base = atomicAdd(cntFix, lcnt);
  __syncthreads();
  if (flag) {
    fixL[base + r] = row;
    float4 z = {0.f, 0.f, 0.f, 0.f};
    ((float4*)(logits + (size_t)row * 8))[0] = z;
    ((float4*)(logits + (size_t)row * 8))[1] = z;
  }
}

// ---------------- pass_count / scan / pass_scatter --------------------------
__global__ __launch_bounds__(256)
void pass_count(const float* __restrict__ logits, const float* __restrict__ b2,
                int* __restrict__ cnts)
{
  __shared__ int lcnt[NEXP];
  const int t = threadIdx.x;
  const int row = blockIdx.x * 256 + t;
  if (t < NEXP) lcnt[t] = 0;
  float l[8]; load_logits(logits, b2, row, l);
  int i0, i1; float l0, l1;
  top2(l, i0, l0, i1, l1);
  __syncthreads();
  atomicAdd(&lcnt[i0], 1);
  atomicAdd(&lcnt[i1], 1);
  __syncthreads();
  if (t < NEXP) atomicAdd(&cnts[t], lcnt[t]);
}

__global__ void scan_kernel(const int* __restrict__ cnts, int* __restrict__ offs,
                            int* __restrict__ tileOffs, int* __restrict__ tileOffs2)
{
  if (threadIdx.x == 0) {
    int s = 0, ts = 0, ts2 = 0;
#pragma unroll
    for (int e = 0; e < NEXP; ++e) {
      offs[e] = s; s += cnts[e];
      tileOffs[e] = ts; ts += (cnts[e] + 127) >> 7;
      tileOffs2[e] = ts2; ts2 += (cnts[e] + 255) >> 8;
    }
    offs[NEXP] = s;
    tileOffs[NEXP] = ts;
    tileOffs2[NEXP] = ts2;
  }
}

__global__ __launch_bounds__(256)
void pass_scatter(const float* __restrict__ logits, const float* __restrict__ b2,
                  const int* __restrict__ offs, int* __restrict__ cnts2,
                  int* __restrict__ rowsC, float* __restrict__ gateC)
{
  __shared__ int lcnt[NEXP];
  __shared__ int sbase[NEXP];
  const int t = threadIdx.x;
  const int row = blockIdx.x * 256 + t;
  if (t < NEXP) lcnt[t] = 0;
  float l[8]; load_logits(logits, b2, row, l);
  int i0, i1; float l0, l1;
  top2(l, i0, l0, i1, l1);
  float tt = expf(l1 - l0);            // <= 1
  float g0 = 1.f / (1.f + tt);
  float g1 = tt / (1.f + tt);
  __syncthreads();
  int r0 = atomicAdd(&lcnt[i0], 1);
  int r1 = atomicAdd(&lcnt[i1], 1);
  __syncthreads();
  if (t < NEXP) sbase[t] = atomicAdd(&cnts2[t], lcnt[t]);
  __syncthreads();
  int p0 = offs[i0] + sbase[i0] + r0;
  int p1 = offs[i1] + sbase[i1] + r1;
  rowsC[p0] = row; gateC[p0] = g0;
  rowsC[p1] = row; gateC[p1] = g1;
}

// ============================================================================
// gemm8p: m201-style 8-phase 256x256 GEMM (grouped or dense), plain HIP.
// BM=BN=256, BK=64. 512 thr = 8 waves (2M x 4N), 128x64 out/wave.
// LDS 128 KiB: As[2 dbuf][2 half][128x64], Bs same. 1 block/CU, 8 waves/CU.
// K-tiles t of 64; slot = t&1. Iter i: compute t0=2i (slot0, phases 1-4) and
// t1=2i+1 (slot1, phases 5-8); stage t1's A (p1,p2), t2's B (p3,p4), t2's A
// (p5,p6), t3's B (p7,p8). Each phase: [subtile ds_reads][1 half-tile stage
// = 2 async16][barrier][setprio 16 MFMA setprio][(vmcnt at p4/p8)][barrier].
// Quadrant order per K-tile: (mfh0,nfh0),(mfh0,nfh1),(mfh1,nfh1),(mfh1,nfh0)
//   - A(mfh) read p1/p3 (8 reads), B(nfh) read p1/p2 (4 reads); both B sets
//     stay live through p4. 16 MFMA per quadrant (4mf x 2nf x 2ks).
// WAR safety: A-halves are wave-private (wave wr reads only half wr; reads end
// p3) -> A stages at p5,p6 safe; B-half reads end p2 -> B stages at p3,p4
// safe; slot1 analogous (reads p5-p7, stages p7-p8 target t3's B only, A of
// t3 staged next-iter p1-p2 > its last read p7).
// vmcnt derivation: p4 end must prove t1 = {B@prev p7p8, A@p1p2}; loads newer
// than A_h1(t1)@p2 = p3(2)+p4(2) -> vmcnt(4). p8 end proves t2 = {B@p3p4,
// A@p5p6}; newer = p7(2)+p8(2) -> vmcnt(4). Prologue: stage t0 (8 loads) then
// B(t1) (4) -> vmcnt(4) proves t0. Last iter (t2>=numK): p3-p8 stages skipped
// -> p4 uses vmcnt(0), p8 no wait.
// LDS swizzle for 128B rows (G4 D=128 pattern): u16 col ^= (row&7)<<3 ->
// 64 lanes spread uniformly 8/16B-slot = LDS BW floor. Applied as
// inverse-swizzled GLOBAL source (linear gload_lds dest) + swizzled ds_read.
// EPI 1: Cbf[(off+m), n] = bf16(relu(acc+bias));  EPI 2: atomicAdd w/ gate.
// DENSE: plain GEMM (router), m-tiles of Mdense/256, e=0.
// ============================================================================
#define G8_BAR() do { __builtin_amdgcn_s_barrier(); \
                      __builtin_amdgcn_sched_barrier(0); } while (0)
#define G8_VM4() asm volatile("s_waitcnt vmcnt(4)" ::: "memory")
#define G8_VM0() asm volatile("s_waitcnt vmcnt(0)" ::: "memory")

#define READ_A(aL, mfh, Af) do { \
  _Pragma("unroll") for (int mf = 0; mf < 4; ++mf) { \
    Af[mf][0] = *(const bf16x8*)&(aL)[((mfh)*4+mf)*1024 + aBase + swzC[0]]; \
    Af[mf][1] = *(const bf16x8*)&(aL)[((mfh)*4+mf)*1024 + aBase + swzC[1]]; \
  } } while (0)

#define READ_B(bL, nfh, Bf) do { \
  _Pragma("unroll") for (int nf = 0; nf < 2; ++nf) { \
    Bf[nf][0] = *(const bf16x8*)&(bL)[((nfh)*2+nf)*1024 + bBase + swzC[0]]; \
    Bf[nf][1] = *(const bf16x8*)&(bL)[((nfh)*2+nf)*1024 + bBase + swzC[1]]; \
  } } while (0)

#define MFMA_Q(mfh, nfh, Af, Bf) do { \
  __builtin_amdgcn_s_setprio(1); \
  _Pragma("unroll") for (int mf = 0; mf < 4; ++mf) \
  _Pragma("unroll") for (int nf = 0; nf < 2; ++nf) { \
    acc[(mfh)*4+mf][(nfh)*2+nf] = __builtin_amdgcn_mfma_f32_16x16x32_bf16( \
        Af[mf][0], Bf[nf][0], acc[(mfh)*4+mf][(nfh)*2+nf], 0, 0, 0); \
    acc[(mfh)*4+mf][(nfh)*2+nf] = __builtin_amdgcn_mfma_f32_16x16x32_bf16( \
        Af[mf][1], Bf[nf][1], acc[(mfh)*4+mf][(nfh)*2+nf], 0, 0, 0); \
  } \
  __builtin_amdgcn_s_setprio(0); } while (0)

template<int EPI, bool GATHER, bool DENSE>
__global__ __launch_bounds__(512, 2)
void gemm8p(const u16* __restrict__ A0, const u16* __restrict__ B0,
            int lda, int ldb, int K, int NT, int Mdense,
            size_t bStrideE, int biasStrideE,
            const int* __restrict__ counts, const int* __restrict__ offs,
            const int* __restrict__ tileOffs,
            const int* __restrict__ rowsC, const float* __restrict__ gatesC,
            const float* __restrict__ bias,
            u16* __restrict__ Cbf, float* __restrict__ Cf32, int ldc)
{
  const unsigned swz = xcd_swz(blockIdx.x, gridDim.x);
  const int mt = (int)(swz / (unsigned)NT);
  int e, m0, Mq, off;
  if constexpr (DENSE) {
    if (mt >= Mdense / 256) return;
    e = 0; m0 = mt * 256; Mq = Mdense; off = 0;
  } else {
    if (mt >= tileOffs[NEXP]) return;
    e = 0;
#pragma unroll
    for (int i = 1; i < NEXP; ++i) if (tileOffs[i] <= mt) e = i;
    m0 = (mt - tileOffs[e]) * 256;
    Mq = counts[e];
    if (m0 >= Mq) return;
    off = offs[e];
  }
  const int n0 = (int)(swz % (unsigned)NT) * 256;
  const int* rows = DENSE ? nullptr : (rowsC + off);
  const u16* B = B0 + (size_t)e * bStrideE;
  const float* bi = bias + (size_t)e * biasStrideE;

  __shared__ alignas(16) u16 As[2][2][128 * 64];   // 64 KiB
  __shared__ alignas(16) u16 Bs[2][2][128 * 64];   // 64 KiB

  const int t = threadIdx.x;          // 0..511
  const int numK = K >> 6;            // K-tiles of 64 (16 or 64; even)

  // ---- staging geometry: half-tile = 128 rows x 64 u16 = 16KB = 2 loads/thr
  // load j: gdx = j*512+t; dest row = gdx>>3, dest 16B-slot = gdx&7.
  // inverse-swizzled source u16 col = ((gdx&7) ^ (row&7)) << 3.
  const u16* aP[2][2]; const u16* bP[2][2]; int dst[2];
#pragma unroll
  for (int j = 0; j < 2; ++j) {
    const int gdx = j * 512 + t;
    const int rw = gdx >> 3;
    const int cs = ((gdx & 7) ^ (rw & 7)) << 3;
    dst[j] = gdx * 8;
#pragma unroll
    for (int h = 0; h < 2; ++h) {
      const int grow = m0 + h * 128 + rw;
      if constexpr (DENSE) {
        aP[h][j] = A0 + (size_t)grow * lda + cs;
      } else {
        const int amc = grow < Mq ? grow : (Mq - 1);
        const size_t agr = GATHER ? (size_t)rows[amc] : (size_t)(off + amc);
        aP[h][j] = A0 + agr * lda + cs;
      }
      bP[h][j] = B + (size_t)(n0 + h * 128 + rw) * ldb + cs;
    }
  }

  auto stA = [&](int tile, int h) {
    async16(aP[h][0] + (size_t)tile * 64, &As[tile & 1][h][dst[0]]);
    async16(aP[h][1] + (size_t)tile * 64, &As[tile & 1][h][dst[1]]);
  };
  auto stB = [&](int tile, int h) {
    async16(bP[h][0] + (size_t)tile * 64, &Bs[tile & 1][h][dst[0]]);
    async16(bP[h][1] + (size_t)tile * 64, &Bs[tile & 1][h][dst[1]]);
  };

  // ---- per-wave fragment geometry ----
  const int lane = t & 63, wv = t >> 6;
  const int wr = wv >> 2;            // 0..1 (A half / 128-row slice)
  const int wc = wv & 3;             // 0..3 (64-col slice; B half = wc>>1)
  const int fr = lane & 15, fq = lane >> 4;

  int swzC[2];
#pragma unroll
  for (int ks = 0; ks < 2; ++ks)
    swzC[ks] = ((ks * 4 + fq) ^ (fr & 7)) << 3;
  const int aBase = fr * 64;
  const int bBase = (wc & 1) * 4096 + fr * 64;

  const u16* aH[2] = { &As[0][wr][0], &As[1][wr][0] };
  const u16* bH[2] = { &Bs[0][wc >> 1][0], &Bs[1][wc >> 1][0] };

  f32x4 acc[8][4];
#pragma unroll
  for (int i = 0; i < 8; ++i)
#pragma unroll
    for (int j = 0; j < 4; ++j) acc[i][j] = (f32x4){0.f, 0.f, 0.f, 0.f};

  // ---- prologue: t0 fully (B,A), then B(t1); prove t0 -> vmcnt(4) ----
  stB(0, 0); stB(0, 1); stA(0, 0); stA(0, 1);
  stB(1, 0); stB(1, 1);
  G8_VM4();
  G8_BAR();

  bf16x8 Af[4][2], Bf0[2][2], Bf1[2][2];

  // ---- main loop: one iter = 2 K-tiles = 8 phases ----
  const int numI = numK >> 1;
  for (int it = 0; it < numI; ++it) {
    const int t1 = 2 * it + 1, t2 = 2 * it + 2, t3 = 2 * it + 3;
    const bool last = (t2 >= numK);
    // P1: read A(mfh0),B(nfh0) of slot0; stage Ah0(t1)
    READ_A(aH[0], 0, Af);
    READ_B(bH[0], 0, Bf0);
    stA(t1, 0);
    G8_BAR();
    MFMA_Q(0, 0, Af, Bf0);
    G8_BAR();
    // P2: read B(nfh1); stage Ah1(t1)
    READ_B(bH[0], 1, Bf1);
    stA(t1, 1);
    G8_BAR();
    MFMA_Q(0, 1, Af, Bf1);
    G8_BAR();
    // P3: read A(mfh1); stage Bh0(t2)
    READ_A(aH[0], 1, Af);
    if (!last) stB(t2, 0);
    G8_BAR();
    MFMA_Q(1, 1, Af, Bf1);
    G8_BAR();
    // P4: stage Bh1(t2); vmcnt proves t1
    if (!last) stB(t2, 1);
    G8_BAR();
    MFMA_Q(1, 0, Af, Bf0);
    if (last) { G8_VM0(); } else { G8_VM4(); }
    G8_BAR();
    // P5: slot1; stage Ah0(t2)
    READ_A(aH[1], 0, Af);
    READ_B(bH[1], 0, Bf0);
    if (!last) stA(t2, 0);
    G8_BAR();
    MFMA_Q(0, 0, Af, Bf0);
    G8_BAR();
    // P6: stage Ah1(t2)
    READ_B(bH[1], 1, Bf1);
    if (!last) stA(t2, 1);
    G8_BAR();
    MFMA_Q(0, 1, Af, Bf1);
    G8_BAR();
    // P7: stage Bh0(t3)
    READ_A(aH[1], 1, Af);
    if (t3 < numK) stB(t3, 0);
    G8_BAR();
    MFMA_Q(1, 1, Af, Bf1);
    G8_BAR();
    // P8: stage Bh1(t3); vmcnt proves t2
    if (t3 < numK) stB(t3, 1);
    G8_BAR();
    MFMA_Q(1, 0, Af, Bf0);
    if (!last) { G8_VM4(); }
    G8_BAR();
  }

  // ---- epilogue: C/D layout col = fr, row = fq*4 + reg ----
  float bv[4];
#pragma unroll
  for (int nf = 0; nf < 4; ++nf) bv[nf] = bi[n0 + wc * 64 + nf * 16 + fr];

  const int crowBase = DENSE ? 0 : off;
#pragma unroll
  for (int mf = 0; mf < 8; ++mf)
#pragma unroll
    for (int r = 0; r < 4; ++r) {
      const int m = m0 + wr * 128 + mf * 16 + fq * 4 + r;
      if (m < Mq) {
        if constexpr (EPI == 2) {
          const size_t orow = (size_t)rows[m];
          const float g = gatesC[off + m];
#pragma unroll
          for (int nf = 0; nf < 4; ++nf) {
            const int n = n0 + wc * 64 + nf * 16 + fr;
            atomicAdd(&Cf32[orow * ldc + n], g * (acc[mf][nf][r] + bv[nf]));
          }
        } else {
#pragma unroll
          for (int nf = 0; nf < 4; ++nf) {
            const int n = n0 + wc * 64 + nf * 16 + fr;
            Cbf[(size_t)(crowBase + m) * ldc + n] =
                f2bf(fmaxf(acc[mf][nf][r] + bv[nf], 0.f));
          }
        }
      }
    }
}

// ---------------- GEMM: C[M,N] = A[M,K] * Bt[N,K]^T (bf16 MFMA) -------------
// (legacy 128x128 kernel: fix-GEMM, non-fused fallback)
template<bool SPLIT, int EPI, bool GATHER>
__global__ __launch_bounds__(256, 2)
void gemm_bt(const u16* __restrict__ A0, const u16* __restrict__ A1,
             const u16* __restrict__ B0, const u16* __restrict__ B1,
             int lda, int ldb, int K, int M,
             const int* __restrict__ counts, int expertArg,
             const int* __restrict__ offs,
             const int* __restrict__ rowsC, const float* __restrict__ gatesC,
             const float* __restrict__ bias,
             const float* __restrict__ w2, float* __restrict__ logits,
             u16* __restrict__ Cbf, float* __restrict__ Cf32, int ldc)
{
  int expert, m0, n0;
  if (counts == nullptr) {
    const unsigned nwg = gridDim.x * gridDim.y;
    const unsigned flat = blockIdx.y * gridDim.x + blockIdx.x;
    const unsigned swz = xcd_swz(flat, nwg);
    expert = expertArg;
    m0 = (int)(swz / gridDim.x) * 128;
    n0 = (int)(swz % gridDim.x) * 128;
  } else {
    expert = expertArg;
    m0 = blockIdx.y * 128;
    n0 = blockIdx.x * 128;
  }

  const int Mq = counts ? counts[expert] : M;
  if (m0 >= Mq) return;
  const int off = offs ? offs[expert] : 0;
  const int* rows = rowsC ? rowsC + off : nullptr;
  const float* gates = gatesC ? gatesC + off : nullptr;
  const u16* B = B0;
  const u16* Bl = SPLIT ? B1 : nullptr;
  const float* bi = bias;
  const int z = (int)blockIdx.z;
  const int zOff = z * K;

  __shared__ u16 As0[128 * 32], Bs0[128 * 32];
  __shared__ u16 As1[SPLIT ? 128 * 32 : 8], Bs1[SPLIT ? 128 * 32 : 8];

  const int t = threadIdx.x;
  size_t aoff[2]; int acodd[2]; size_t boff[2];
#pragma unroll
  for (int i = 0; i < 2; ++i) {
    int gdx = i * 256 + t;
    int ar = gdx >> 2, ac = (gdx & 3) * 8;
    int am = m0 + ar;
    int amc = am < Mq ? am : (Mq - 1);
    int agr = GATHER ? rows[amc] : amc;
    aoff[i] = (size_t)agr * lda + ac + zOff;
    boff[i] = (size_t)(n0 + ar) * ldb + ac + zOff;
    acodd[i] = gdx * 8;
  }

  f32x4 acc[4][4];
#pragma unroll
  for (int i = 0; i < 4; ++i)
#pragma unroll
    for (int j = 0; j < 4; ++j) acc[i][j] = (f32x4){0.f, 0.f, 0.f, 0.f};

  const int lane = t & 63, wv = t >> 6;
  const int wm = (wv >> 1) * 64, wn = (wv & 1) * 64;
  const int fr = lane & 15, fq = lane >> 4;

  for (int k0 = 0; k0 < K; k0 += 32) {
    __syncthreads();
#pragma unroll
    for (int i = 0; i < 2; ++i) {
      async16(A0 + aoff[i] + k0, &As0[acodd[i]]);
      async16(B + boff[i] + k0, &Bs0[acodd[i]]);
      if (SPLIT) {
        async16(A1 + aoff[i] + k0, &As1[acodd[i]]);
        async16(Bl + boff[i] + k0, &Bs1[acodd[i]]);
      }
    }
    __syncthreads();
    bf16x8 af[4], bfr[4], af1[4], bf1[4];
#pragma unroll
    for (int xi = 0; xi < 4; ++xi) {
      af[xi]  = *(const bf16x8*)&As0[(wm + xi * 16 + fr) * 32 + fq * 8];
      bfr[xi] = *(const bf16x8*)&Bs0[(wn + xi * 16 + fr) * 32 + fq * 8];
      if (SPLIT) {
        af1[xi] = *(const bf16x8*)&As1[(wm + xi * 16 + fr) * 32 + fq * 8];
        bf1[xi] = *(const bf16x8*)&Bs1[(wn + xi * 16 + fr) * 32 + fq * 8];
      }
    }
#pragma unroll
    for (int mt = 0; mt < 4; ++mt)
#pragma unroll
      for (int nt = 0; nt < 4; ++nt) {
        acc[mt][nt] = __builtin_amdgcn_mfma_f32_16x16x32_bf16(af[mt], bfr[nt], acc[mt][nt], 0, 0, 0);
        if (SPLIT) {
          acc[mt][nt] = __builtin_amdgcn_mfma_f32_16x16x32_bf16(af[mt], bf1[nt], acc[mt][nt], 0, 0, 0);
          acc[mt][nt] = __builtin_amdgcn_mfma_f32_16x16x32_bf16(af1[mt], bfr[nt], acc[mt][nt], 0, 0, 0);
        }
      }
  }

  // C/D layout: col = lane&15 (fr), row = fq*4 + reg
  if constexpr (EPI == 3) {
    float w2v[4][8]; float b1v[4];
#pragma unroll
    for (int nt = 0; nt < 4; ++nt) {
      const int n = n0 + wn + nt * 16 + fr;
      b1v[nt] = bi[n];
      const float4* wp = (const float4*)(w2 + (size_t)n * 8);
      float4 wa = wp[0], wb = wp[1];
      w2v[nt][0] = wa.x; w2v[nt][1] = wa.y; w2v[nt][2] = wa.z; w2v[nt][3] = wa.w;
      w2v[nt][4] = wb.x; w2v[nt][5] = wb.y; w2v[nt][6] = wb.z; w2v[nt][7] = wb.w;
    }
#pragma unroll
    for (int mt = 0; mt < 4; ++mt) {
      float pe[4][8];
#pragma unroll
      for (int r = 0; r < 4; ++r)
#pragma unroll
        for (int ee = 0; ee < 8; ++ee) pe[r][ee] = 0.f;
#pragma unroll
      for (int nt = 0; nt < 4; ++nt)
#pragma unroll
        for (int r = 0; r < 4; ++r) {
          float v = fmaxf(acc[mt][nt][r] + b1v[nt], 0.f);
#pragma unroll
          for (int ee = 0; ee < 8; ++ee) pe[r][ee] += v * w2v[nt][ee];
        }
#pragma unroll
      for (int offx = 1; offx < 16; offx <<= 1)
#pragma unroll
        for (int r = 0; r < 4; ++r)
#pragma unroll
          for (int ee = 0; ee < 8; ++ee)
            pe[r][ee] += __shfl_xor(pe[r][ee], offx, 64);
      if (fr == 0) {
#pragma unroll
        for (int r = 0; r < 4; ++r) {
          const int m = m0 + wm + mt * 16 + fq * 4 + r;
          if (m < Mq) {
            const int lrow = GATHER ? rows[m] : m;
#pragma unroll
            for (int ee = 0; ee < 8; ++ee)
              atomicAdd(&logits[(size_t)lrow * 8 + ee], pe[r][ee]);
          }
        }
      }
    }
    return;
  }

#pragma unroll
  for (int mt = 0; mt < 4; ++mt) {
#pragma unroll
    for (int nt = 0; nt < 4; ++nt) {
      const int n = n0 + wn + nt * 16 + fr;
      const float bvv = (z == 0) ? bi[n] : 0.f;
#pragma unroll
      for (int r = 0; r < 4; ++r) {
        const int m = m0 + wm + mt * 16 + fq * 4 + r;
        if (m < Mq) {
          float v = acc[mt][nt][r] + bvv;
          if constexpr (EPI == 1) {
            Cbf[(size_t)m * ldc + n] = f2bf(fmaxf(v, 0.f));
          } else {
            atomicAdd(&Cf32[(size_t)rows[m] * ldc + n], gates[m] * v);
          }
        }
      }
    }
  }
}

extern "C" void kernel_launch(void* const* d_in, const int* in_sizes, int n_in,
                              void* d_out, int out_size, void* d_ws, size_t ws_size,
                              hipStream_t stream)
{
  const float* x    = (const float*)d_in[0];
  const float* ln_g = (const float*)d_in[1];
  const float* ln_b = (const float*)d_in[2];
  const float* r_w1 = (const float*)d_in[3];
  const float* r_b1 = (const float*)d_in[4];
  const float* r_w2 = (const float*)d_in[5];
  const float* r_b2 = (const float*)d_in[6];
  const float* e_w1 = (const float*)d_in[7];
  const float* e_b1 = (const float*)d_in[8];
  const float* e_w2 = (const float*)d_in[9];
  const float* e_b2 = (const float*)d_in[10];
  float* out = (float*)d_out;

  char* ws = (char*)d_ws;
  const size_t MB = 1024ull * 1024ull;
  u16*   xnhi = (u16*)(ws);                 // 32 MB  [N, D] bf16
  u16*   xnlo = (u16*)(ws + 32 * MB);       // 32 MB
  u16*   rw1h = (u16*)(ws + 64 * MB);       // 4 MB   [HR, D] bf16
  u16*   rw1l = (u16*)(ws + 68 * MB);       // 4 MB
  u16*   ew1t = (u16*)(ws + 72 * MB);       // 64 MB  [E][H, D] bf16
  u16*   ew2t = (u16*)(ws + 136 * MB);      // 64 MB  [E][D, H] bf16
  float* logits = (float*)(ws + 200 * MB);                    // 512 KB [N, 8]
  int*   rowsC  = (int*)(ws + 200 * MB + 512 * 1024);         // 128 KB [2N]
  float* gateC  = (float*)(ws + 200 * MB + 640 * 1024);       // 128 KB [2N]
  int*   fixL   = (int*)(ws + 200 * MB + 768 * 1024);         // 64 KB  [N]
  int*   cntb   = (int*)(ws + 200 * MB + 832 * 1024);         // 256 B
  int*   cnts   = cntb;          // [8]
  int*   cnts2  = cntb + 8;      // [8]
  int*   offs   = cntb + 16;     // [9]
  int*   cntFix = cntb + 25;     // [1]
  int*   tileOffs  = cntb + 32;  // [9] per-expert 128-row tile prefix sums
  int*   tileOffs2 = cntb + 48;  // [9] per-expert 256-row tile prefix sums
  u16*   Hbuf = (u16*)(ws + 201 * MB);      // fused: 256 MB [2N, H]; HrB aliases
  u16*   HrB  = Hbuf;                       // 64 MB [N, HR] bf16 (router hidden)
  (void)in_sizes; (void)n_in; (void)out_size;

  const bool fused = ws_size >= 458ull * MB;

  hipMemsetAsync(cntb, 0, 256, stream);

  dim3 tb(32, 8);
  transpose_cvt<true ><<<dim3(HR / 32, DIM / 32, 1), tb, 0, stream>>>(r_w1, rw1h, rw1l, DIM, HR);
  transpose_cvt<false><<<dim3(HID / 32, DIM / 32, NEXP), tb, 0, stream>>>(e_w1, ew1t, nullptr, DIM, HID);
  transpose_cvt<false><<<dim3(DIM / 32, HID / 32, NEXP), tb, 0, stream>>>(e_w2, ew2t, nullptr, HID, DIM);

  ln_kernel<<<N_TOK, 256, 0, stream>>>(x, ln_g, ln_b, xnhi, xnlo, out);

  // router: HrB = bf16(relu(xn @ r_w1 + b1)) — 8-phase DENSE, 512 blocks
  gemm8p<1, false, true><<<dim3((HR / 256) * (N_TOK / 256)), 512, 0, stream>>>(
      xnhi, rw1h, DIM, DIM, DIM, HR / 256, N_TOK, 0, 0,
      nullptr, nullptr, nullptr, nullptr, nullptr, r_b1,
      HrB, nullptr, HR);

  logits_kernel<<<N_TOK, 256, 0, stream>>>(HrB, r_w2, logits);

  pass_flag<<<N_TOK / 256, 256, 0, stream>>>(logits, r_b2, fixL, cntFix);

  // exact recompute (split 3-term) of flagged rows' logits
  gemm_bt<true, 3, true><<<dim3(HR / 128, N_TOK / 128), 256, 0, stream>>>(
      xnhi, xnlo, rw1h, rw1l, DIM, DIM, DIM, N_TOK,
      cntFix, 0, nullptr, fixL, nullptr, r_b1, r_w2, logits,
      nullptr, nullptr, 0);

  pass_count<<<N_TOK / 256, 256, 0, stream>>>(logits, r_b2, cnts);
  scan_kernel<<<1, 64, 0, stream>>>(cnts, offs, tileOffs, tileOffs2);
  pass_scatter<<<N_TOK / 256, 256, 0, stream>>>(logits, r_b2, offs, cnts2, rowsC, gateC);

  if (fused) {
    // 8-phase grouped GEMMs: 256x256 tiles, flat compacted grid + XCD swizzle
    gemm8p<1, true, false><<<dim3((HID / 256) * MAXMT2), 512, 0, stream>>>(
        xnhi, ew1t, DIM, DIM, DIM, HID / 256, 0,
        (size_t)HID * DIM, HID,
        cnts, offs, tileOffs2, rowsC, nullptr, e_b1,
        Hbuf, nullptr, HID);
    gemm8p<2, false, false><<<dim3((DIM / 256) * MAXMT2), 512, 0, stream>>>(
        Hbuf, ew2t, HID, HID, HID, DIM / 256, 0,
        (size_t)DIM * HID, DIM,
        cnts, offs, tileOffs2, rowsC, gateC, e_b2,
        nullptr, out, DIM);
  } else {
    for (int e = 0; e < NEXP; ++e) {
      gemm_bt<false, 1, true><<<dim3(HID / 128, N_TOK / 128), 256, 0, stream>>>(
          xnhi, nullptr, ew1t + (size_t)e * HID * DIM, nullptr,
          DIM, DIM, DIM, N_TOK,
          cnts, e, offs, rowsC, nullptr, e_b1 + (size_t)e * HID, nullptr, nullptr,
          Hbuf, nullptr, HID);
      gemm_bt<false, 2, false><<<dim3(DIM / 128, N_TOK / 128, 2), 256, 0, stream>>>(
          Hbuf, nullptr, ew2t + (size_t)e * DIM * HID, nullptr,
          HID, HID, HID / 2, N_TOK,
          cnts, e, offs, rowsC, gateC, e_b2 + (size_t)e * DIM, nullptr, nullptr,
          nullptr, out, DIM);
    }
  }
}